// Round 2
// baseline (1467.891 us; speedup 1.0000x reference)
//
#include <hip/hip_runtime.h>
#include <math.h>

// ---- problem constants ----
#define LQ 4096
#define MTOK 8192
#define HID 2048
#define NHEADS 16
#define DHEAD 64
#define ENG 1024
#define VOCAB 129280
#define HC 4
#define EPS_RMS 1.1920929e-07f
#define EPS_SC  1e-05f
#define INV_SQRT_HID 0.022097086912079608f  // 1/sqrt(2048)

typedef __bf16 bf16;
typedef __attribute__((ext_vector_type(8))) __bf16 bf16x8;
typedef __attribute__((ext_vector_type(4))) __bf16 bf16x4;
typedef __attribute__((ext_vector_type(4))) float f32x4;

#define AS1 __attribute__((address_space(1)))
#define AS3 __attribute__((address_space(3)))

__device__ __forceinline__ void gl_lds16(const void* g, void* l) {
    __builtin_amdgcn_global_load_lds((const AS1 unsigned int*)g,
                                     (AS3 unsigned int*)l, 16, 0, 0);
}

// ============================================================
// 1) gather -> bf16 emb [MTOK][ENG]
// ============================================================
__global__ __launch_bounds__(256) void gather_kernel(
        const int* __restrict__ hash_ids,
        const float* __restrict__ emb_tables,
        bf16* __restrict__ emb)
{
    int t = blockIdx.x;
    int tid = threadIdx.x;
    const int* ids = hash_ids + (size_t)t * NHEADS;
    int k = tid * 4;
    int h = k >> 6, d = k & 63;
    int id = ids[h];
    float4 v = *(const float4*)(emb_tables + ((size_t)h * VOCAB + (size_t)id) * DHEAD + d);
    bf16x4 o = {(bf16)v.x, (bf16)v.y, (bf16)v.z, (bf16)v.w};
    *(bf16x4*)(emb + (size_t)t * ENG + k) = o;
}

// ============================================================
// 2) transpose+convert weights: [ENG][HID] fp32 -> [HID][ENG] bf16
// ============================================================
__global__ __launch_bounds__(256) void transpose_kernel(
        const float* __restrict__ value_w,
        const float* __restrict__ key_w,
        bf16* __restrict__ vwT,
        bf16* __restrict__ kwT)
{
    __shared__ float tile[32][33];
    int z = blockIdx.z;
    const float* src = (z == 0) ? value_w : key_w + (size_t)(z - 1) * ENG * HID;
    bf16* dst = (z == 0) ? vwT : kwT + (size_t)(z - 1) * HID * ENG;
    int c0 = blockIdx.x * 32, r0 = blockIdx.y * 32;
    int tx = threadIdx.x & 31, ty = threadIdx.x >> 5;
    #pragma unroll
    for (int i = 0; i < 4; ++i)
        tile[ty + i * 8][tx] = src[(size_t)(r0 + ty + i * 8) * HID + c0 + tx];
    __syncthreads();
    #pragma unroll
    for (int i = 0; i < 4; ++i)
        dst[(size_t)(c0 + ty + i * 8) * ENG + r0 + tx] = (bf16)tile[tx][ty + i * 8];
}

// ============================================================
// 8-phase pipelined 256x256 GEMM core (T3+T4+T5, counted vmcnt).
// LDS half-tile = K-half: sX[buf*2+kh][256 rows][32 k], 16 KB each.
// Per K-tile (BK=64): 4 phases = (fmh,ks) quadrants of 16 MFMA.
// Stage map at tile t: ph0->(t+1).B0  ph1->(t+1).A1  ph2->(t+1).B1
//                      ph3->(t+2).A0 ; vmcnt(6) after MM at ph1, ph3.
// Read/stage chunk swizzle: 16B chunk c holds logical k-chunk c^(row&3).
// ============================================================
#define BARRIER() asm volatile("s_barrier" ::: "memory")
#define WAITVM(N) asm volatile("s_waitcnt vmcnt(" #N ")" ::: "memory")

#define ST_A(buf, kh, tt) { \
    int k0_ = (tt) * 64 + (kh) * 32; \
    _Pragma("unroll") \
    for (int j_ = 0; j_ < 2; ++j_) { \
        int st_ = w * 2 + j_; \
        int r_ = st_ * 16 + lrow; \
        gl_lds16(Asrc + (size_t)(arow0 + r_) * ENG + k0_ + ((lc ^ (r_ & 3)) * 8), \
                 &sA[(buf) * 2 + (kh)][st_ * 16][0]); \
    } }

#define ST_B(buf, kh, tt) { \
    int k0_ = (tt) * 64 + (kh) * 32; \
    _Pragma("unroll") \
    for (int j_ = 0; j_ < 2; ++j_) { \
        int st_ = w * 2 + j_; \
        int r_ = st_ * 16 + lrow; \
        gl_lds16(Bsrc + (size_t)(brow0 + r_) * ENG + k0_ + ((lc ^ (r_ & 3)) * 8), \
                 &sB[(buf) * 2 + (kh)][st_ * 16][0]); \
    } }

#define LD_A(fmh, buf, ks) { \
    _Pragma("unroll") \
    for (int f_ = 0; f_ < 4; ++f_) { \
        int r_ = wm + (fmh) * 64 + f_ * 16 + lane15; \
        af[f_] = *(const bf16x8*)&sA[(buf) * 2 + (ks)][r_][(quad ^ r3) * 8]; \
    } }

#define LD_B(buf, ks) { \
    _Pragma("unroll") \
    for (int f_ = 0; f_ < 4; ++f_) { \
        int r_ = wn + f_ * 16 + lane15; \
        bfr[f_] = *(const bf16x8*)&sB[(buf) * 2 + (ks)][r_][(quad ^ r3) * 8]; \
    } }

#define MM(fmh) { \
    __builtin_amdgcn_s_setprio(1); \
    _Pragma("unroll") \
    for (int f_ = 0; f_ < 4; ++f_) \
        _Pragma("unroll") \
        for (int fn_ = 0; fn_ < 4; ++fn_) \
            acc[(fmh) * 4 + f_][fn_] = __builtin_amdgcn_mfma_f32_16x16x32_bf16( \
                af[f_], bfr[fn_], acc[(fmh) * 4 + f_][fn_], 0, 0, 0); \
    __builtin_amdgcn_s_setprio(0); }

#define GEMM_PIPELINE() \
    ST_A(0, 0, 0); ST_B(0, 0, 0); ST_A(0, 1, 0); ST_B(0, 1, 0); ST_A(1, 0, 1); \
    WAITVM(6); BARRIER(); \
    for (int t = 0; t < 14; ++t) { \
        int bc = t & 1, bn = bc ^ 1; \
        LD_A(0, bc, 0); LD_B(bc, 0); ST_B(bn, 0, t + 1); \
        BARRIER(); MM(0); BARRIER(); \
        LD_A(1, bc, 0); ST_A(bn, 1, t + 1); \
        BARRIER(); MM(1); WAITVM(6); BARRIER(); \
        LD_A(0, bc, 1); LD_B(bc, 1); ST_B(bn, 1, t + 1); \
        BARRIER(); MM(0); BARRIER(); \
        LD_A(1, bc, 1); ST_A(bc, 0, t + 2); \
        BARRIER(); MM(1); WAITVM(6); BARRIER(); \
    } \
    /* tile 14 (buf 0) */ \
    LD_A(0, 0, 0); LD_B(0, 0); ST_B(1, 0, 15); BARRIER(); MM(0); BARRIER(); \
    LD_A(1, 0, 0); ST_A(1, 1, 15);             BARRIER(); MM(1); WAITVM(6); BARRIER(); \
    LD_A(0, 0, 1); LD_B(0, 1); ST_B(1, 1, 15); BARRIER(); MM(0); BARRIER(); \
    LD_A(1, 0, 1);                             BARRIER(); MM(1); WAITVM(4); BARRIER(); \
    /* tile 15 (buf 1) */ \
    LD_A(0, 1, 0); LD_B(1, 0); BARRIER(); MM(0); BARRIER(); \
    LD_A(1, 1, 0);             BARRIER(); MM(1); WAITVM(0); BARRIER(); \
    LD_A(0, 1, 1); LD_B(1, 1); BARRIER(); MM(0); BARRIER(); \
    LD_A(1, 1, 1);             BARRIER(); MM(1); BARRIER();

// ============================================================
// 3) value MFMA GEMM: vraw = emb @ value_w + b, fused sum(vraw^2)
// ============================================================
__global__ __launch_bounds__(512, 2) void gemm_value_mfma(
        const bf16* __restrict__ A,
        const bf16* __restrict__ Bt,
        const float* __restrict__ bias,
        float* __restrict__ C,
        float* __restrict__ pv2)
{
    __shared__ __align__(1024) bf16 sA[4][256][32];
    __shared__ __align__(1024) bf16 sB[4][256][32];
    int tid = threadIdx.x;
    int L = tid & 63, w = tid >> 6;
    int nwgx = gridDim.x;
    int nwg  = nwgx * gridDim.y;
    int bid  = blockIdx.y * nwgx + blockIdx.x;
    int cpx  = nwg >> 3;
    int swz  = (bid & 7) * cpx + (bid >> 3);
    int m0 = (swz / nwgx) * 256;
    int n0 = (swz % nwgx) * 256;
    int wm = (w & 1) * 128, wn = (w >> 1) * 64;
    int lane15 = L & 15, quad = L >> 4, r3 = lane15 & 3;
    int lrow = L >> 2, lc = L & 3;
    const bf16* Asrc = A;  const bf16* Bsrc = Bt;
    int arow0 = m0, brow0 = n0;

    f32x4 acc[8][4];
    #pragma unroll
    for (int fm = 0; fm < 8; ++fm)
        #pragma unroll
        for (int fn = 0; fn < 4; ++fn)
            acc[fm][fn] = (f32x4){0.f, 0.f, 0.f, 0.f};
    bf16x8 af[4], bfr[4];

    GEMM_PIPELINE();

    // epilogue: C = acc + bias, pv2[m] += sum_n v^2
    #pragma unroll
    for (int fm = 0; fm < 8; ++fm) {
        #pragma unroll
        for (int r = 0; r < 4; ++r) {
            int m = m0 + wm + fm * 16 + quad * 4 + r;
            float sv = 0.f;
            #pragma unroll
            for (int fn = 0; fn < 4; ++fn) {
                int n = n0 + wn + fn * 16 + lane15;
                float v = acc[fm][fn][r] + bias[n];
                C[(size_t)m * HID + n] = v;
                sv += v * v;
            }
            sv += __shfl_xor(sv, 1); sv += __shfl_xor(sv, 2);
            sv += __shfl_xor(sv, 4); sv += __shfl_xor(sv, 8);
            if (lane15 == 0) atomicAdd(&pv2[m], sv);
        }
    }
}

// ============================================================
// 4) keys MFMA GEMM, fused gate partials (keys never stored)
// ============================================================
__global__ __launch_bounds__(512, 2) void gemm_keys_mfma(
        const bf16* __restrict__ A,
        const bf16* __restrict__ kwT,    // [HC][HID][ENG] bf16
        const float* __restrict__ key_b, // [HC][HID]
        const float* __restrict__ hidden,// [MTOK][HID] fp32
        const float* __restrict__ w1,
        const float* __restrict__ w2,
        float* __restrict__ p_sq,        // [MTOK][HC]
        float* __restrict__ p_dot)       // [MTOK][HC]
{
    __shared__ __align__(1024) bf16 sA[4][256][32];
    __shared__ __align__(1024) bf16 sB[4][256][32];
    int tid = threadIdx.x;
    int L = tid & 63, w = tid >> 6;
    int nwgx = gridDim.x;
    int nwg  = nwgx * gridDim.y;
    int bid  = blockIdx.y * nwgx + blockIdx.x;
    int cpx  = nwg >> 3;
    int swz  = (bid & 7) * cpx + (bid >> 3);
    int m0 = (swz / nwgx) * 256;
    int c0 = (swz % nwgx) * 256;
    int g   = c0 >> 11;
    int nc0 = c0 & (HID - 1);
    int wm = (w & 1) * 128, wn = (w >> 1) * 64;
    int lane15 = L & 15, quad = L >> 4, r3 = lane15 & 3;
    int lrow = L >> 2, lc = L & 3;
    const bf16* Asrc = A;
    const bf16* Bsrc = kwT + (size_t)g * HID * ENG;
    int arow0 = m0, brow0 = nc0;

    f32x4 acc[8][4];
    #pragma unroll
    for (int fm = 0; fm < 8; ++fm)
        #pragma unroll
        for (int fn = 0; fn < 4; ++fn)
            acc[fm][fn] = (f32x4){0.f, 0.f, 0.f, 0.f};
    bf16x8 af[4], bfr[4];

    GEMM_PIPELINE();

    // epilogue: per-row partials of keys^2 and keys*hid*w1*w2
    const float* kb  = key_b + (size_t)g * HID;
    const float* w1g = w1 + (size_t)g * HID;
    const float* w2g = w2 + (size_t)g * HID;
    #pragma unroll
    for (int fm = 0; fm < 8; ++fm) {
        #pragma unroll
        for (int r = 0; r < 4; ++r) {
            int m = m0 + wm + fm * 16 + quad * 4 + r;
            float psq = 0.f, pdt = 0.f;
            #pragma unroll
            for (int fn = 0; fn < 4; ++fn) {
                int nc = nc0 + wn + fn * 16 + lane15;
                float v = acc[fm][fn][r] + kb[nc];
                float hv = hidden[(size_t)m * HID + nc];
                float ww = w1g[nc] * w2g[nc];
                psq += v * v;
                pdt += v * hv * ww;
            }
            psq += __shfl_xor(psq, 1); psq += __shfl_xor(psq, 2);
            psq += __shfl_xor(psq, 4); psq += __shfl_xor(psq, 8);
            pdt += __shfl_xor(pdt, 1); pdt += __shfl_xor(pdt, 2);
            pdt += __shfl_xor(pdt, 4); pdt += __shfl_xor(pdt, 8);
            if (lane15 == 0) {
                atomicAdd(&p_sq[(size_t)m * HC + g], psq);
                atomicAdd(&p_dot[(size_t)m * HC + g], pdt);
            }
        }
    }
}

// ============================================================
// 5) mq = mean(hidden^2) per token — one wave per token
// ============================================================
__global__ __launch_bounds__(256) void mq_kernel(
        const float* __restrict__ hidden, float* __restrict__ mq)
{
    int w = threadIdx.x >> 6, L = threadIdx.x & 63;
    int t = blockIdx.x * 4 + w;
    const float4* hp = (const float4*)(hidden + (size_t)t * HID);
    float s = 0.f;
    #pragma unroll
    for (int i = 0; i < 8; ++i) {
        float4 h = hp[L + i * 64];
        s += h.x * h.x + h.y * h.y + h.z * h.z + h.w * h.w;
    }
    #pragma unroll
    for (int msk = 1; msk < 64; msk <<= 1) s += __shfl_xor(s, msk);
    if (L == 0) mq[t] = s * (1.0f / HID);
}

// ============================================================
// 6) gate finalize
// ============================================================
__global__ __launch_bounds__(256) void finalize_kernel(
        const float* __restrict__ p_sq,
        const float* __restrict__ p_dot,
        const float* __restrict__ mq,
        const float* __restrict__ pv2,
        float* __restrict__ gate,
        float* __restrict__ cc)
{
    int i = blockIdx.x * 256 + threadIdx.x;
    if (i >= MTOK * HC) return;
    int t = i >> 2;
    float mk = p_sq[i] * (1.0f / HID) + EPS_RMS;
    float mqv = mq[t] + EPS_RMS;
    float raw = p_dot[i] * rsqrtf(mk) * rsqrtf(mqv) * INV_SQRT_HID;
    float g2 = copysignf(sqrtf(fmaxf(fabsf(raw), 1e-6f)), raw);
    float gt = 1.0f / (1.0f + expf(-g2));
    gate[i] = gt;
    float msqv = pv2[t] * (1.0f / HID);
    cc[i] = gt * rsqrtf(gt * gt * msqv + EPS_SC);
}

// ============================================================
// 7) fused conv + silu + gated-value + channel sum
// ============================================================
__global__ __launch_bounds__(256) void final_kernel(
        const float* __restrict__ vraw,
        const float* __restrict__ gate,
        const float* __restrict__ cc,
        const float* __restrict__ sc_w,   // [HC][HID]
        const float* __restrict__ conv_w, // [HC*HID][4]
        float* __restrict__ out)
{
    int t = blockIdx.x;
    int l = t & (LQ - 1);
    int tid = threadIdx.x;
    float G = gate[t * 4 + 0] + gate[t * 4 + 1] + gate[t * 4 + 2] + gate[t * 4 + 3];
    float cg[4][4];
    int tki[4];
    #pragma unroll
    for (int k = 0; k < 4; ++k) {
        int lk = l + 3 * k - 9;
        bool valid = (lk >= 0);
        int tk = t + 3 * k - 9;
        tki[k] = valid ? tk : -1;
        #pragma unroll
        for (int g = 0; g < 4; ++g)
            cg[k][g] = valid ? cc[tk * 4 + g] : 0.0f;
    }
    #pragma unroll
    for (int i = 0; i < 2; ++i) {
        int h4 = tid + i * 256;
        float4 vk[4];
        #pragma unroll
        for (int k = 0; k < 4; ++k) {
            vk[k] = (tki[k] >= 0)
                  ? ((const float4*)(vraw + (size_t)tki[k] * HID))[h4]
                  : make_float4(0.f, 0.f, 0.f, 0.f);
        }
        float res[4];
        #pragma unroll
        for (int j = 0; j < 4; ++j) {
            int h = h4 * 4 + j;
            float vt = ((const float*)&vk[3])[j];
            float o = vt * G;
            #pragma unroll
            for (int g = 0; g < 4; ++g) {
                float4 w4 = ((const float4*)conv_w)[(size_t)g * HID + h];
                float y = w4.x * cg[0][g] * ((const float*)&vk[0])[j]
                        + w4.y * cg[1][g] * ((const float*)&vk[1])[j]
                        + w4.z * cg[2][g] * ((const float*)&vk[2])[j]
                        + w4.w * cg[3][g] * ((const float*)&vk[3])[j];
                y *= sc_w[(size_t)g * HID + h];
                o += y / (1.0f + expf(-y));
            }
            res[j] = o;
        }
        ((float4*)(out + (size_t)t * HID))[h4] = make_float4(res[0], res[1], res[2], res[3]);
    }
}

// ============================================================
extern "C" void kernel_launch(void* const* d_in, const int* in_sizes, int n_in,
                              void* d_out, int out_size, void* d_ws, size_t ws_size,
                              hipStream_t stream)
{
    const float* hidden     = (const float*)d_in[0];
    const int*   hash_ids   = (const int*)  d_in[1];
    const float* emb_tables = (const float*)d_in[2];
    const float* value_w    = (const float*)d_in[3];
    const float* value_b    = (const float*)d_in[4];
    const float* key_w      = (const float*)d_in[5];
    const float* key_b      = (const float*)d_in[6];
    const float* norm1_w    = (const float*)d_in[7];
    const float* norm2_w    = (const float*)d_in[8];
    const float* sc_norm_w  = (const float*)d_in[9];
    const float* conv_w     = (const float*)d_in[10];
    float* out = (float*)d_out;

    char* ws = (char*)d_ws;
    bf16*  ws_emb  = (bf16*)ws;  ws += sizeof(bf16) * (size_t)MTOK * ENG;        // 16 MB
    bf16*  ws_vwT  = (bf16*)ws;  ws += sizeof(bf16) * (size_t)HID * ENG;         // 4 MB
    bf16*  ws_kwT  = (bf16*)ws;  ws += sizeof(bf16) * (size_t)HC * HID * ENG;    // 16 MB
    float* ws_vraw = (float*)ws; ws += sizeof(float) * (size_t)MTOK * HID;       // 64 MB
    float* ws_psq  = (float*)ws; ws += sizeof(float) * (size_t)MTOK * HC;
    float* ws_pdot = (float*)ws; ws += sizeof(float) * (size_t)MTOK * HC;
    float* ws_pv2  = (float*)ws; ws += sizeof(float) * (size_t)MTOK;
    float* ws_mq   = (float*)ws; ws += sizeof(float) * (size_t)MTOK;
    float* ws_gate = (float*)ws; ws += sizeof(float) * (size_t)MTOK * HC;
    float* ws_cc   = (float*)ws; ws += sizeof(float) * (size_t)MTOK * HC;

    // zero atomic accumulators (psq, pdot, pv2 are contiguous)
    hipMemsetAsync(ws_psq, 0, sizeof(float) * ((size_t)MTOK * HC * 2 + MTOK), stream);

    transpose_kernel<<<dim3(HID / 32, ENG / 32, 5), 256, 0, stream>>>(
        value_w, key_w, ws_vwT, ws_kwT);

    gather_kernel<<<MTOK, 256, 0, stream>>>(hash_ids, emb_tables, ws_emb);

    gemm_value_mfma<<<dim3(HID / 256, MTOK / 256), 512, 0, stream>>>(
        ws_emb, ws_vwT, value_b, ws_vraw, ws_pv2);

    gemm_keys_mfma<<<dim3(HC * HID / 256, MTOK / 256), 512, 0, stream>>>(
        ws_emb, ws_kwT, key_b, hidden, norm1_w, norm2_w, ws_psq, ws_pdot);

    mq_kernel<<<MTOK / 4, 256, 0, stream>>>(hidden, ws_mq);

    finalize_kernel<<<(MTOK * HC + 255) / 256, 256, 0, stream>>>(
        ws_psq, ws_pdot, ws_mq, ws_pv2, ws_gate, ws_cc);

    final_kernel<<<MTOK, 256, 0, stream>>>(
        ws_vraw, ws_gate, ws_cc, sc_norm_w, conv_w, out);
}

// Round 3
// 1403.143 us; speedup vs baseline: 1.0461x; 1.0461x over previous
//
#include <hip/hip_runtime.h>
#include <math.h>

// ---- problem constants ----
#define LQ 4096
#define MTOK 8192
#define HID 2048
#define NHEADS 16
#define DHEAD 64
#define ENG 1024
#define VOCAB 129280
#define HC 4
#define EPS_RMS 1.1920929e-07f
#define EPS_SC  1e-05f
#define INV_SQRT_HID 0.022097086912079608f  // 1/sqrt(2048)

typedef __bf16 bf16;
typedef __attribute__((ext_vector_type(8))) __bf16 bf16x8;
typedef __attribute__((ext_vector_type(4))) __bf16 bf16x4;
typedef __attribute__((ext_vector_type(4))) float f32x4;

#define AS1 __attribute__((address_space(1)))
#define AS3 __attribute__((address_space(3)))

__device__ __forceinline__ void gl_lds16(const void* g, void* l) {
    __builtin_amdgcn_global_load_lds((const AS1 unsigned int*)g,
                                     (AS3 unsigned int*)l, 16, 0, 0);
}

// ============================================================
// 1) gather -> bf16 emb [MTOK][ENG]
// ============================================================
__global__ __launch_bounds__(256) void gather_kernel(
        const int* __restrict__ hash_ids,
        const float* __restrict__ emb_tables,
        bf16* __restrict__ emb)
{
    int t = blockIdx.x;
    int tid = threadIdx.x;
    const int* ids = hash_ids + (size_t)t * NHEADS;
    int k = tid * 4;
    int h = k >> 6, d = k & 63;
    int id = ids[h];
    float4 v = *(const float4*)(emb_tables + ((size_t)h * VOCAB + (size_t)id) * DHEAD + d);
    bf16x4 o = {(bf16)v.x, (bf16)v.y, (bf16)v.z, (bf16)v.w};
    *(bf16x4*)(emb + (size_t)t * ENG + k) = o;
}

// ============================================================
// 2) transpose+convert weights: [ENG][HID] fp32 -> [HID][ENG] bf16
// ============================================================
__global__ __launch_bounds__(256) void transpose_kernel(
        const float* __restrict__ value_w,
        const float* __restrict__ key_w,
        bf16* __restrict__ vwT,
        bf16* __restrict__ kwT)
{
    __shared__ float tile[32][33];
    int z = blockIdx.z;
    const float* src = (z == 0) ? value_w : key_w + (size_t)(z - 1) * ENG * HID;
    bf16* dst = (z == 0) ? vwT : kwT + (size_t)(z - 1) * HID * ENG;
    int c0 = blockIdx.x * 32, r0 = blockIdx.y * 32;
    int tx = threadIdx.x & 31, ty = threadIdx.x >> 5;
    #pragma unroll
    for (int i = 0; i < 4; ++i)
        tile[ty + i * 8][tx] = src[(size_t)(r0 + ty + i * 8) * HID + c0 + tx];
    __syncthreads();
    #pragma unroll
    for (int i = 0; i < 4; ++i)
        dst[(size_t)(c0 + ty + i * 8) * ENG + r0 + tx] = (bf16)tile[tx][ty + i * 8];
}

// ============================================================
// 3) value MFMA GEMM: 256x256x64 tiles, 2-phase LDS double-buffer
//    NOTE: __launch_bounds__(512) with NO min-waves arg — a min-waves
//    of 2 clamps the unified reg budget to 128/wave and spills the
//    128-AGPR accumulator (R1/R2 regression).
// ============================================================
__global__ __launch_bounds__(512) void gemm_value_mfma(
        const bf16* __restrict__ A,
        const bf16* __restrict__ Bt,
        const float* __restrict__ bias,
        float* __restrict__ C,
        float* __restrict__ pv2)
{
    __shared__ __align__(16) bf16 sA[2][256 * 64];
    __shared__ __align__(16) bf16 sB[2][256 * 64];
    int tid = threadIdx.x;
    int L = tid & 63, w = tid >> 6;            // 8 waves
    // T1: bijective XCD swizzle (nwg % 8 == 0)
    int nwgx = gridDim.x;
    int nwg  = nwgx * gridDim.y;
    int bid  = blockIdx.y * nwgx + blockIdx.x;
    int cpx  = nwg >> 3;
    int swz  = (bid & 7) * cpx + (bid >> 3);
    int m0 = (swz / nwgx) * 256;
    int n0 = (swz % nwgx) * 256;
    int wm = (w & 1) * 128, wn = (w >> 1) * 64;  // wave sub-tile: 128x64
    int lrow = L >> 3;
    int kcS = ((L & 7) ^ lrow) * 8;     // XOR pre-swizzled global k-offset
    int lane15 = L & 15, quad = L >> 4;

    f32x4 acc[8][4];
    #pragma unroll
    for (int fm = 0; fm < 8; ++fm)
        #pragma unroll
        for (int fn = 0; fn < 4; ++fn)
            acc[fm][fn] = (f32x4){0.f, 0.f, 0.f, 0.f};

    auto STAGE = [&](int buf, int k0) {
        #pragma unroll
        for (int i = 0; i < 4; ++i) {
            int seg = w * 4 + i;                 // 32 segs of 8 rows each
            gl_lds16(A  + (size_t)(m0 + seg * 8 + lrow) * ENG + k0 + kcS,
                     &sA[buf][seg * 512]);
            gl_lds16(Bt + (size_t)(n0 + seg * 8 + lrow) * ENG + k0 + kcS,
                     &sB[buf][seg * 512]);
        }
    };
    auto COMPUTE = [&](int buf) {
        #pragma unroll
        for (int ks = 0; ks < 2; ++ks) {
            int kc = ks * 4 + quad;
            bf16x8 bfr[4];
            #pragma unroll
            for (int f = 0; f < 4; ++f) {
                int rb = wn + f * 16 + lane15;
                bfr[f] = *(const bf16x8*)(&sB[buf][rb * 64 + ((kc ^ (rb & 7)) * 8)]);
            }
            #pragma unroll
            for (int fmh = 0; fmh < 2; ++fmh) {
                bf16x8 af[4];
                #pragma unroll
                for (int f = 0; f < 4; ++f) {
                    int ra = wm + fmh * 64 + f * 16 + lane15;
                    af[f] = *(const bf16x8*)(&sA[buf][ra * 64 + ((kc ^ (ra & 7)) * 8)]);
                }
                __builtin_amdgcn_s_setprio(1);
                #pragma unroll
                for (int f = 0; f < 4; ++f)
                    #pragma unroll
                    for (int fn = 0; fn < 4; ++fn)
                        acc[fmh * 4 + f][fn] = __builtin_amdgcn_mfma_f32_16x16x32_bf16(
                            af[f], bfr[fn], acc[fmh * 4 + f][fn], 0, 0, 0);
                __builtin_amdgcn_s_setprio(0);
            }
        }
    };

    // 2-phase pipeline: stage t+1 before computing t; one drain/barrier per tile
    STAGE(0, 0);
    __syncthreads();
    int cur = 0;
    for (int t = 0; t < ENG / 64 - 1; ++t) {
        STAGE(cur ^ 1, (t + 1) * 64);
        COMPUTE(cur);
        __syncthreads();
        cur ^= 1;
    }
    COMPUTE(cur);

    // epilogue: C = acc + bias, pv2[m] += sum_n v^2
    #pragma unroll
    for (int fm = 0; fm < 8; ++fm) {
        #pragma unroll
        for (int r = 0; r < 4; ++r) {
            int m = m0 + wm + fm * 16 + quad * 4 + r;
            float sv = 0.f;
            #pragma unroll
            for (int fn = 0; fn < 4; ++fn) {
                int n = n0 + wn + fn * 16 + lane15;
                float v = acc[fm][fn][r] + bias[n];
                C[(size_t)m * HID + n] = v;
                sv += v * v;
            }
            sv += __shfl_xor(sv, 1); sv += __shfl_xor(sv, 2);
            sv += __shfl_xor(sv, 4); sv += __shfl_xor(sv, 8);
            if (lane15 == 0) atomicAdd(&pv2[m], sv);
        }
    }
}

// ============================================================
// 4) keys MFMA GEMM: 256x256x64 tiles, 2-phase LDS double-buffer
//    fused gate partials (keys never stored)
// ============================================================
__global__ __launch_bounds__(512) void gemm_keys_mfma(
        const bf16* __restrict__ A,
        const bf16* __restrict__ kwT,    // [HC][HID][ENG] bf16
        const float* __restrict__ key_b, // [HC][HID]
        const float* __restrict__ hidden,// [MTOK][HID] fp32
        const float* __restrict__ w1,
        const float* __restrict__ w2,
        float* __restrict__ p_sq,        // [MTOK][HC]
        float* __restrict__ p_dot)       // [MTOK][HC]
{
    __shared__ __align__(16) bf16 sA[2][256 * 64];
    __shared__ __align__(16) bf16 sB[2][256 * 64];
    int tid = threadIdx.x;
    int L = tid & 63, w = tid >> 6;
    int nwgx = gridDim.x;
    int nwg  = nwgx * gridDim.y;
    int bid  = blockIdx.y * nwgx + blockIdx.x;
    int cpx  = nwg >> 3;
    int swz  = (bid & 7) * cpx + (bid >> 3);
    int m0 = (swz / nwgx) * 256;
    int c0 = (swz % nwgx) * 256;        // col in [0, HC*HID)
    int g   = c0 >> 11;
    int nc0 = c0 & (HID - 1);
    const bf16* Bt = kwT + (size_t)g * HID * ENG;
    int wm = (w & 1) * 128, wn = (w >> 1) * 64;
    int lrow = L >> 3;
    int kcS = ((L & 7) ^ lrow) * 8;
    int lane15 = L & 15, quad = L >> 4;

    f32x4 acc[8][4];
    #pragma unroll
    for (int fm = 0; fm < 8; ++fm)
        #pragma unroll
        for (int fn = 0; fn < 4; ++fn)
            acc[fm][fn] = (f32x4){0.f, 0.f, 0.f, 0.f};

    auto STAGE = [&](int buf, int k0) {
        #pragma unroll
        for (int i = 0; i < 4; ++i) {
            int seg = w * 4 + i;
            gl_lds16(A  + (size_t)(m0  + seg * 8 + lrow) * ENG + k0 + kcS,
                     &sA[buf][seg * 512]);
            gl_lds16(Bt + (size_t)(nc0 + seg * 8 + lrow) * ENG + k0 + kcS,
                     &sB[buf][seg * 512]);
        }
    };
    auto COMPUTE = [&](int buf) {
        #pragma unroll
        for (int ks = 0; ks < 2; ++ks) {
            int kc = ks * 4 + quad;
            bf16x8 bfr[4];
            #pragma unroll
            for (int f = 0; f < 4; ++f) {
                int rb = wn + f * 16 + lane15;
                bfr[f] = *(const bf16x8*)(&sB[buf][rb * 64 + ((kc ^ (rb & 7)) * 8)]);
            }
            #pragma unroll
            for (int fmh = 0; fmh < 2; ++fmh) {
                bf16x8 af[4];
                #pragma unroll
                for (int f = 0; f < 4; ++f) {
                    int ra = wm + fmh * 64 + f * 16 + lane15;
                    af[f] = *(const bf16x8*)(&sA[buf][ra * 64 + ((kc ^ (ra & 7)) * 8)]);
                }
                __builtin_amdgcn_s_setprio(1);
                #pragma unroll
                for (int f = 0; f < 4; ++f)
                    #pragma unroll
                    for (int fn = 0; fn < 4; ++fn)
                        acc[fmh * 4 + f][fn] = __builtin_amdgcn_mfma_f32_16x16x32_bf16(
                            af[f], bfr[fn], acc[fmh * 4 + f][fn], 0, 0, 0);
                __builtin_amdgcn_s_setprio(0);
            }
        }
    };

    STAGE(0, 0);
    __syncthreads();
    int cur = 0;
    for (int t = 0; t < ENG / 64 - 1; ++t) {
        STAGE(cur ^ 1, (t + 1) * 64);
        COMPUTE(cur);
        __syncthreads();
        cur ^= 1;
    }
    COMPUTE(cur);

    // epilogue: per-row partials of keys^2 and keys*hid*w1*w2
    const float* kb  = key_b + (size_t)g * HID;
    const float* w1g = w1 + (size_t)g * HID;
    const float* w2g = w2 + (size_t)g * HID;
    #pragma unroll
    for (int fm = 0; fm < 8; ++fm) {
        #pragma unroll
        for (int r = 0; r < 4; ++r) {
            int m = m0 + wm + fm * 16 + quad * 4 + r;
            float psq = 0.f, pdt = 0.f;
            #pragma unroll
            for (int fn = 0; fn < 4; ++fn) {
                int nc = nc0 + wn + fn * 16 + lane15;
                float v = acc[fm][fn][r] + kb[nc];
                float hv = hidden[(size_t)m * HID + nc];
                float ww = w1g[nc] * w2g[nc];
                psq += v * v;
                pdt += v * hv * ww;
            }
            psq += __shfl_xor(psq, 1); psq += __shfl_xor(psq, 2);
            psq += __shfl_xor(psq, 4); psq += __shfl_xor(psq, 8);
            pdt += __shfl_xor(pdt, 1); pdt += __shfl_xor(pdt, 2);
            pdt += __shfl_xor(pdt, 4); pdt += __shfl_xor(pdt, 8);
            if (lane15 == 0) {
                atomicAdd(&p_sq[(size_t)m * HC + g], psq);
                atomicAdd(&p_dot[(size_t)m * HC + g], pdt);
            }
        }
    }
}

// ============================================================
// 5) mq = mean(hidden^2) per token — one wave per token
// ============================================================
__global__ __launch_bounds__(256) void mq_kernel(
        const float* __restrict__ hidden, float* __restrict__ mq)
{
    int w = threadIdx.x >> 6, L = threadIdx.x & 63;
    int t = blockIdx.x * 4 + w;
    const float4* hp = (const float4*)(hidden + (size_t)t * HID);
    float s = 0.f;
    #pragma unroll
    for (int i = 0; i < 8; ++i) {
        float4 h = hp[L + i * 64];
        s += h.x * h.x + h.y * h.y + h.z * h.z + h.w * h.w;
    }
    #pragma unroll
    for (int msk = 1; msk < 64; msk <<= 1) s += __shfl_xor(s, msk);
    if (L == 0) mq[t] = s * (1.0f / HID);
}

// ============================================================
// 6) gate finalize
// ============================================================
__global__ __launch_bounds__(256) void finalize_kernel(
        const float* __restrict__ p_sq,
        const float* __restrict__ p_dot,
        const float* __restrict__ mq,
        const float* __restrict__ pv2,
        float* __restrict__ gate,
        float* __restrict__ cc)
{
    int i = blockIdx.x * 256 + threadIdx.x;
    if (i >= MTOK * HC) return;
    int t = i >> 2;
    float mk = p_sq[i] * (1.0f / HID) + EPS_RMS;
    float mqv = mq[t] + EPS_RMS;
    float raw = p_dot[i] * rsqrtf(mk) * rsqrtf(mqv) * INV_SQRT_HID;
    float g2 = copysignf(sqrtf(fmaxf(fabsf(raw), 1e-6f)), raw);
    float gt = 1.0f / (1.0f + expf(-g2));
    gate[i] = gt;
    float msqv = pv2[t] * (1.0f / HID);
    cc[i] = gt * rsqrtf(gt * gt * msqv + EPS_SC);
}

// ============================================================
// 7) fused conv + silu + gated-value + channel sum
// ============================================================
__global__ __launch_bounds__(256) void final_kernel(
        const float* __restrict__ vraw,
        const float* __restrict__ gate,
        const float* __restrict__ cc,
        const float* __restrict__ sc_w,   // [HC][HID]
        const float* __restrict__ conv_w, // [HC*HID][4]
        float* __restrict__ out)
{
    int t = blockIdx.x;
    int l = t & (LQ - 1);
    int tid = threadIdx.x;
    float G = gate[t * 4 + 0] + gate[t * 4 + 1] + gate[t * 4 + 2] + gate[t * 4 + 3];
    float cg[4][4];
    int tki[4];
    #pragma unroll
    for (int k = 0; k < 4; ++k) {
        int lk = l + 3 * k - 9;
        bool valid = (lk >= 0);
        int tk = t + 3 * k - 9;
        tki[k] = valid ? tk : -1;
        #pragma unroll
        for (int g = 0; g < 4; ++g)
            cg[k][g] = valid ? cc[tk * 4 + g] : 0.0f;
    }
    #pragma unroll
    for (int i = 0; i < 2; ++i) {
        int h4 = tid + i * 256;
        float4 vk[4];
        #pragma unroll
        for (int k = 0; k < 4; ++k) {
            vk[k] = (tki[k] >= 0)
                  ? ((const float4*)(vraw + (size_t)tki[k] * HID))[h4]
                  : make_float4(0.f, 0.f, 0.f, 0.f);
        }
        float res[4];
        #pragma unroll
        for (int j = 0; j < 4; ++j) {
            int h = h4 * 4 + j;
            float vt = ((const float*)&vk[3])[j];
            float o = vt * G;
            #pragma unroll
            for (int g = 0; g < 4; ++g) {
                float4 w4 = ((const float4*)conv_w)[(size_t)g * HID + h];
                float y = w4.x * cg[0][g] * ((const float*)&vk[0])[j]
                        + w4.y * cg[1][g] * ((const float*)&vk[1])[j]
                        + w4.z * cg[2][g] * ((const float*)&vk[2])[j]
                        + w4.w * cg[3][g] * ((const float*)&vk[3])[j];
                y *= sc_w[(size_t)g * HID + h];
                o += y / (1.0f + expf(-y));
            }
            res[j] = o;
        }
        ((float4*)(out + (size_t)t * HID))[h4] = make_float4(res[0], res[1], res[2], res[3]);
    }
}

// ============================================================
extern "C" void kernel_launch(void* const* d_in, const int* in_sizes, int n_in,
                              void* d_out, int out_size, void* d_ws, size_t ws_size,
                              hipStream_t stream)
{
    const float* hidden     = (const float*)d_in[0];
    const int*   hash_ids   = (const int*)  d_in[1];
    const float* emb_tables = (const float*)d_in[2];
    const float* value_w    = (const float*)d_in[3];
    const float* value_b    = (const float*)d_in[4];
    const float* key_w      = (const float*)d_in[5];
    const float* key_b      = (const float*)d_in[6];
    const float* norm1_w    = (const float*)d_in[7];
    const float* norm2_w    = (const float*)d_in[8];
    const float* sc_norm_w  = (const float*)d_in[9];
    const float* conv_w     = (const float*)d_in[10];
    float* out = (float*)d_out;

    char* ws = (char*)d_ws;
    bf16*  ws_emb  = (bf16*)ws;  ws += sizeof(bf16) * (size_t)MTOK * ENG;        // 16 MB
    bf16*  ws_vwT  = (bf16*)ws;  ws += sizeof(bf16) * (size_t)HID * ENG;         // 4 MB
    bf16*  ws_kwT  = (bf16*)ws;  ws += sizeof(bf16) * (size_t)HC * HID * ENG;    // 16 MB
    float* ws_vraw = (float*)ws; ws += sizeof(float) * (size_t)MTOK * HID;       // 64 MB
    float* ws_psq  = (float*)ws; ws += sizeof(float) * (size_t)MTOK * HC;
    float* ws_pdot = (float*)ws; ws += sizeof(float) * (size_t)MTOK * HC;
    float* ws_pv2  = (float*)ws; ws += sizeof(float) * (size_t)MTOK;
    float* ws_mq   = (float*)ws; ws += sizeof(float) * (size_t)MTOK;
    float* ws_gate = (float*)ws; ws += sizeof(float) * (size_t)MTOK * HC;
    float* ws_cc   = (float*)ws; ws += sizeof(float) * (size_t)MTOK * HC;

    // zero atomic accumulators (psq, pdot, pv2 are contiguous)
    hipMemsetAsync(ws_psq, 0, sizeof(float) * ((size_t)MTOK * HC * 2 + MTOK), stream);

    transpose_kernel<<<dim3(HID / 32, ENG / 32, 5), 256, 0, stream>>>(
        value_w, key_w, ws_vwT, ws_kwT);

    gather_kernel<<<MTOK, 256, 0, stream>>>(hash_ids, emb_tables, ws_emb);

    gemm_value_mfma<<<dim3(HID / 256, MTOK / 256), 512, 0, stream>>>(
        ws_emb, ws_vwT, value_b, ws_vraw, ws_pv2);

    gemm_keys_mfma<<<dim3(HC * HID / 256, MTOK / 256), 512, 0, stream>>>(
        ws_emb, ws_kwT, key_b, hidden, norm1_w, norm2_w, ws_psq, ws_pdot);

    mq_kernel<<<MTOK / 4, 256, 0, stream>>>(hidden, ws_mq);

    finalize_kernel<<<(MTOK * HC + 255) / 256, 256, 0, stream>>>(
        ws_psq, ws_pdot, ws_mq, ws_pv2, ws_gate, ws_cc);

    final_kernel<<<MTOK, 256, 0, stream>>>(
        ws_vraw, ws_gate, ws_cc, sc_norm_w, conv_w, out);
}

// Round 4
// 1056.311 us; speedup vs baseline: 1.3896x; 1.3283x over previous
//
#include <hip/hip_runtime.h>
#include <math.h>

// ---- problem constants ----
#define LQ 4096
#define MTOK 8192
#define HID 2048
#define NHEADS 16
#define DHEAD 64
#define ENG 1024
#define VOCAB 129280
#define HC 4
#define EPS_RMS 1.1920929e-07f
#define EPS_SC  1e-05f
#define INV_SQRT_HID 0.022097086912079608f  // 1/sqrt(2048)

typedef __bf16 bf16;
typedef __attribute__((ext_vector_type(8))) __bf16 bf16x8;
typedef __attribute__((ext_vector_type(4))) __bf16 bf16x4;
typedef __attribute__((ext_vector_type(4))) float f32x4;

#define AS1 __attribute__((address_space(1)))
#define AS3 __attribute__((address_space(3)))

__device__ __forceinline__ void gl_lds16(const void* g, void* l) {
    __builtin_amdgcn_global_load_lds((const AS1 unsigned int*)g,
                                     (AS3 unsigned int*)l, 16, 0, 0);
}

// ============================================================
// 1) gather -> bf16 emb [MTOK][ENG]
// ============================================================
__global__ __launch_bounds__(256) void gather_kernel(
        const int* __restrict__ hash_ids,
        const float* __restrict__ emb_tables,
        bf16* __restrict__ emb)
{
    int t = blockIdx.x;
    int tid = threadIdx.x;
    const int* ids = hash_ids + (size_t)t * NHEADS;
    int k = tid * 4;
    int h = k >> 6, d = k & 63;
    int id = ids[h];
    float4 v = *(const float4*)(emb_tables + ((size_t)h * VOCAB + (size_t)id) * DHEAD + d);
    bf16x4 o = {(bf16)v.x, (bf16)v.y, (bf16)v.z, (bf16)v.w};
    *(bf16x4*)(emb + (size_t)t * ENG + k) = o;
}

// ============================================================
// 2) transpose+convert weights: [ENG][HID] fp32 -> [HID][ENG] bf16
//    z==0: value_w, z=1..4: key_w channel z-1
// ============================================================
__global__ __launch_bounds__(256) void transpose_kernel(
        const float* __restrict__ value_w,
        const float* __restrict__ key_w,
        bf16* __restrict__ vwT,
        bf16* __restrict__ kwT)
{
    __shared__ float tile[32][33];
    int z = blockIdx.z;
    const float* src = (z == 0) ? value_w : key_w + (size_t)(z - 1) * ENG * HID;
    bf16* dst = (z == 0) ? vwT : kwT + (size_t)(z - 1) * HID * ENG;
    int c0 = blockIdx.x * 32, r0 = blockIdx.y * 32;
    int tx = threadIdx.x & 31, ty = threadIdx.x >> 5;   // ty: 0..7
    #pragma unroll
    for (int i = 0; i < 4; ++i)
        tile[ty + i * 8][tx] = src[(size_t)(r0 + ty + i * 8) * HID + c0 + tx];
    __syncthreads();
    #pragma unroll
    for (int i = 0; i < 4; ++i)
        dst[(size_t)(c0 + ty + i * 8) * ENG + r0 + tx] = (bf16)tile[tx][ty + i * 8];
}

// ============================================================
// 3) value MFMA GEMM (R0-proven 128x128 structure).
//    Grid remap: blockIdx.x = m-block (fast) -> consecutive blocks
//    share the same 256KB B column-panel (L2-resident), A streams.
// ============================================================
__global__ __launch_bounds__(256, 1) void gemm_value_mfma(
        const bf16* __restrict__ A,
        const bf16* __restrict__ Bt,
        const float* __restrict__ bias,
        float* __restrict__ C,
        float* __restrict__ pv2)
{
    __shared__ __align__(16) bf16 sA[128 * 64];
    __shared__ __align__(16) bf16 sB[128 * 64];
    int tid = threadIdx.x;
    int L = tid & 63, w = tid >> 6;
    int m0 = blockIdx.x * 128, n0 = blockIdx.y * 128;   // x = m (fast)
    int mw = (w & 1) * 64, nw = (w >> 1) * 64;
    int lrow = L >> 3;
    int kcS = ((L & 7) ^ lrow) * 8;     // XOR-swizzled k elem offset for staging
    int lane15 = L & 15, quad = L >> 4;

    f32x4 acc[4][4];
    #pragma unroll
    for (int fm = 0; fm < 4; ++fm)
        #pragma unroll
        for (int fn = 0; fn < 4; ++fn)
            acc[fm][fn] = (f32x4){0.f, 0.f, 0.f, 0.f};

    for (int k0 = 0; k0 < ENG; k0 += 64) {
        #pragma unroll
        for (int i = 0; i < 4; ++i) {
            int seg = w * 4 + i;
            gl_lds16(A + (size_t)(m0 + seg * 8 + lrow) * ENG + k0 + kcS, sA + seg * 512);
            gl_lds16(Bt + (size_t)(n0 + seg * 8 + lrow) * ENG + k0 + kcS, sB + seg * 512);
        }
        __syncthreads();
        #pragma unroll
        for (int ks = 0; ks < 2; ++ks) {
            bf16x8 af[4], bfr[4];
            int kc = ks * 4 + quad;
            #pragma unroll
            for (int f = 0; f < 4; ++f) {
                int ra = mw + f * 16 + lane15;
                int rb = nw + f * 16 + lane15;
                af[f]  = *(const bf16x8*)(sA + ra * 64 + ((kc ^ (ra & 7)) * 8));
                bfr[f] = *(const bf16x8*)(sB + rb * 64 + ((kc ^ (rb & 7)) * 8));
            }
            #pragma unroll
            for (int fm = 0; fm < 4; ++fm)
                #pragma unroll
                for (int fn = 0; fn < 4; ++fn)
                    acc[fm][fn] = __builtin_amdgcn_mfma_f32_16x16x32_bf16(
                        af[fm], bfr[fn], acc[fm][fn], 0, 0, 0);
        }
        __syncthreads();
    }
    // epilogue: C = acc + bias, p_v2[m] += sum_n v^2
    #pragma unroll
    for (int fm = 0; fm < 4; ++fm) {
        #pragma unroll
        for (int r = 0; r < 4; ++r) {
            int m = m0 + mw + fm * 16 + quad * 4 + r;
            float sv = 0.f;
            #pragma unroll
            for (int fn = 0; fn < 4; ++fn) {
                int n = n0 + nw + fn * 16 + lane15;
                float v = acc[fm][fn][r] + bias[n];
                C[(size_t)m * HID + n] = v;
                sv += v * v;
            }
            sv += __shfl_xor(sv, 1); sv += __shfl_xor(sv, 2);
            sv += __shfl_xor(sv, 4); sv += __shfl_xor(sv, 8);
            if (lane15 == 0) atomicAdd(&pv2[m], sv);
        }
    }
}

// ============================================================
// 4) keys MFMA GEMM (R0-proven structure), fused gate partials.
//    Grid remap: blockIdx.x = m-block (fast); blockIdx.y enumerates
//    (nc-block, channel) CHANNEL-FAST so the 4 channels sharing the
//    same hidden column-slice run concurrently (hidden read 1x from
//    HBM instead of 4x; A panel reused across the 4 col-panels).
// ============================================================
__global__ __launch_bounds__(256, 1) void gemm_keys_mfma(
        const bf16* __restrict__ A,
        const bf16* __restrict__ kwT,    // [HC][HID][ENG] bf16
        const float* __restrict__ key_b, // [HC][HID]
        const float* __restrict__ hidden,// [MTOK][HID] fp32
        const float* __restrict__ w1,
        const float* __restrict__ w2,
        float* __restrict__ p_sq,        // [MTOK][HC]
        float* __restrict__ p_dot)       // [MTOK][HC]
{
    __shared__ __align__(16) bf16 sA[128 * 64];
    __shared__ __align__(16) bf16 sB[128 * 64];
    int tid = threadIdx.x;
    int L = tid & 63, w = tid >> 6;
    int m0 = blockIdx.x * 128;          // x = m (fast)
    int y  = blockIdx.y;
    int g   = y & 3;                    // channel-fast
    int nc0 = (y >> 2) * 128;           // col within channel
    const bf16* Bt = kwT + (size_t)g * HID * ENG;
    int mw = (w & 1) * 64, nw = (w >> 1) * 64;
    int lrow = L >> 3;
    int kcS = ((L & 7) ^ lrow) * 8;
    int lane15 = L & 15, quad = L >> 4;

    f32x4 acc[4][4];
    #pragma unroll
    for (int fm = 0; fm < 4; ++fm)
        #pragma unroll
        for (int fn = 0; fn < 4; ++fn)
            acc[fm][fn] = (f32x4){0.f, 0.f, 0.f, 0.f};

    for (int k0 = 0; k0 < ENG; k0 += 64) {
        #pragma unroll
        for (int i = 0; i < 4; ++i) {
            int seg = w * 4 + i;
            gl_lds16(A  + (size_t)(m0  + seg * 8 + lrow) * ENG + k0 + kcS, sA + seg * 512);
            gl_lds16(Bt + (size_t)(nc0 + seg * 8 + lrow) * ENG + k0 + kcS, sB + seg * 512);
        }
        __syncthreads();
        #pragma unroll
        for (int ks = 0; ks < 2; ++ks) {
            bf16x8 af[4], bfr[4];
            int kc = ks * 4 + quad;
            #pragma unroll
            for (int f = 0; f < 4; ++f) {
                int ra = mw + f * 16 + lane15;
                int rb = nw + f * 16 + lane15;
                af[f]  = *(const bf16x8*)(sA + ra * 64 + ((kc ^ (ra & 7)) * 8));
                bfr[f] = *(const bf16x8*)(sB + rb * 64 + ((kc ^ (rb & 7)) * 8));
            }
            #pragma unroll
            for (int fm = 0; fm < 4; ++fm)
                #pragma unroll
                for (int fn = 0; fn < 4; ++fn)
                    acc[fm][fn] = __builtin_amdgcn_mfma_f32_16x16x32_bf16(
                        af[fm], bfr[fn], acc[fm][fn], 0, 0, 0);
        }
        __syncthreads();
    }
    // epilogue: per-row partials of keys^2 and keys*hid*w1*w2
    const float* kb  = key_b + (size_t)g * HID;
    const float* w1g = w1 + (size_t)g * HID;
    const float* w2g = w2 + (size_t)g * HID;
    #pragma unroll
    for (int fm = 0; fm < 4; ++fm) {
        #pragma unroll
        for (int r = 0; r < 4; ++r) {
            int m = m0 + mw + fm * 16 + quad * 4 + r;
            float psq = 0.f, pdt = 0.f;
            #pragma unroll
            for (int fn = 0; fn < 4; ++fn) {
                int nc = nc0 + nw + fn * 16 + lane15;
                float v = acc[fm][fn][r] + kb[nc];
                float hv = hidden[(size_t)m * HID + nc];
                float ww = w1g[nc] * w2g[nc];
                psq += v * v;
                pdt += v * hv * ww;
            }
            psq += __shfl_xor(psq, 1); psq += __shfl_xor(psq, 2);
            psq += __shfl_xor(psq, 4); psq += __shfl_xor(psq, 8);
            pdt += __shfl_xor(pdt, 1); pdt += __shfl_xor(pdt, 2);
            pdt += __shfl_xor(pdt, 4); pdt += __shfl_xor(pdt, 8);
            if (lane15 == 0) {
                atomicAdd(&p_sq[(size_t)m * HC + g], psq);
                atomicAdd(&p_dot[(size_t)m * HC + g], pdt);
            }
        }
    }
}

// ============================================================
// 5) mq = mean(hidden^2) per token — one wave per token
// ============================================================
__global__ __launch_bounds__(256) void mq_kernel(
        const float* __restrict__ hidden, float* __restrict__ mq)
{
    int w = threadIdx.x >> 6, L = threadIdx.x & 63;
    int t = blockIdx.x * 4 + w;
    const float4* hp = (const float4*)(hidden + (size_t)t * HID);
    float s = 0.f;
    #pragma unroll
    for (int i = 0; i < 8; ++i) {
        float4 h = hp[L + i * 64];
        s += h.x * h.x + h.y * h.y + h.z * h.z + h.w * h.w;
    }
    #pragma unroll
    for (int msk = 1; msk < 64; msk <<= 1) s += __shfl_xor(s, msk);
    if (L == 0) mq[t] = s * (1.0f / HID);
}

// ============================================================
// 6) gate finalize
// ============================================================
__global__ __launch_bounds__(256) void finalize_kernel(
        const float* __restrict__ p_sq,
        const float* __restrict__ p_dot,
        const float* __restrict__ mq,
        const float* __restrict__ pv2,
        float* __restrict__ gate,
        float* __restrict__ cc)
{
    int i = blockIdx.x * 256 + threadIdx.x;
    if (i >= MTOK * HC) return;
    int t = i >> 2;
    float mk = p_sq[i] * (1.0f / HID) + EPS_RMS;
    float mqv = mq[t] + EPS_RMS;
    float raw = p_dot[i] * rsqrtf(mk) * rsqrtf(mqv) * INV_SQRT_HID;
    float g2 = copysignf(sqrtf(fmaxf(fabsf(raw), 1e-6f)), raw);
    float gt = 1.0f / (1.0f + expf(-g2));
    gate[i] = gt;
    float msqv = pv2[t] * (1.0f / HID);
    cc[i] = gt * rsqrtf(gt * gt * msqv + EPS_SC);
}

// ============================================================
// 7) fused conv + silu + gated-value + channel sum
// ============================================================
__global__ __launch_bounds__(256) void final_kernel(
        const float* __restrict__ vraw,
        const float* __restrict__ gate,
        const float* __restrict__ cc,
        const float* __restrict__ sc_w,   // [HC][HID]
        const float* __restrict__ conv_w, // [HC*HID][4]
        float* __restrict__ out)
{
    int t = blockIdx.x;
    int l = t & (LQ - 1);
    int tid = threadIdx.x;
    float G = gate[t * 4 + 0] + gate[t * 4 + 1] + gate[t * 4 + 2] + gate[t * 4 + 3];
    float cg[4][4];
    int tki[4];
    #pragma unroll
    for (int k = 0; k < 4; ++k) {
        int lk = l + 3 * k - 9;
        bool valid = (lk >= 0);
        int tk = t + 3 * k - 9;
        tki[k] = valid ? tk : -1;
        #pragma unroll
        for (int g = 0; g < 4; ++g)
            cg[k][g] = valid ? cc[tk * 4 + g] : 0.0f;
    }
    #pragma unroll
    for (int i = 0; i < 2; ++i) {
        int h4 = tid + i * 256;
        float4 vk[4];
        #pragma unroll
        for (int k = 0; k < 4; ++k) {
            vk[k] = (tki[k] >= 0)
                  ? ((const float4*)(vraw + (size_t)tki[k] * HID))[h4]
                  : make_float4(0.f, 0.f, 0.f, 0.f);
        }
        float res[4];
        #pragma unroll
        for (int j = 0; j < 4; ++j) {
            int h = h4 * 4 + j;
            float vt = ((const float*)&vk[3])[j];
            float o = vt * G;
            #pragma unroll
            for (int g = 0; g < 4; ++g) {
                float4 w4 = ((const float4*)conv_w)[(size_t)g * HID + h];
                float y = w4.x * cg[0][g] * ((const float*)&vk[0])[j]
                        + w4.y * cg[1][g] * ((const float*)&vk[1])[j]
                        + w4.z * cg[2][g] * ((const float*)&vk[2])[j]
                        + w4.w * cg[3][g] * ((const float*)&vk[3])[j];
                y *= sc_w[(size_t)g * HID + h];
                o += y / (1.0f + expf(-y));
            }
            res[j] = o;
        }
        ((float4*)(out + (size_t)t * HID))[h4] = make_float4(res[0], res[1], res[2], res[3]);
    }
}

// ============================================================
extern "C" void kernel_launch(void* const* d_in, const int* in_sizes, int n_in,
                              void* d_out, int out_size, void* d_ws, size_t ws_size,
                              hipStream_t stream)
{
    const float* hidden     = (const float*)d_in[0];
    const int*   hash_ids   = (const int*)  d_in[1];
    const float* emb_tables = (const float*)d_in[2];
    const float* value_w    = (const float*)d_in[3];
    const float* value_b    = (const float*)d_in[4];
    const float* key_w      = (const float*)d_in[5];
    const float* key_b      = (const float*)d_in[6];
    const float* norm1_w    = (const float*)d_in[7];
    const float* norm2_w    = (const float*)d_in[8];
    const float* sc_norm_w  = (const float*)d_in[9];
    const float* conv_w     = (const float*)d_in[10];
    float* out = (float*)d_out;

    char* ws = (char*)d_ws;
    bf16*  ws_emb  = (bf16*)ws;  ws += sizeof(bf16) * (size_t)MTOK * ENG;        // 16 MB
    bf16*  ws_vwT  = (bf16*)ws;  ws += sizeof(bf16) * (size_t)HID * ENG;         // 4 MB
    bf16*  ws_kwT  = (bf16*)ws;  ws += sizeof(bf16) * (size_t)HC * HID * ENG;    // 16 MB
    float* ws_vraw = (float*)ws; ws += sizeof(float) * (size_t)MTOK * HID;       // 64 MB
    float* ws_psq  = (float*)ws; ws += sizeof(float) * (size_t)MTOK * HC;
    float* ws_pdot = (float*)ws; ws += sizeof(float) * (size_t)MTOK * HC;
    float* ws_pv2  = (float*)ws; ws += sizeof(float) * (size_t)MTOK;
    float* ws_mq   = (float*)ws; ws += sizeof(float) * (size_t)MTOK;
    float* ws_gate = (float*)ws; ws += sizeof(float) * (size_t)MTOK * HC;
    float* ws_cc   = (float*)ws; ws += sizeof(float) * (size_t)MTOK * HC;

    // zero atomic accumulators (psq, pdot, pv2 are contiguous)
    hipMemsetAsync(ws_psq, 0, sizeof(float) * ((size_t)MTOK * HC * 2 + MTOK), stream);

    transpose_kernel<<<dim3(HID / 32, ENG / 32, 5), 256, 0, stream>>>(
        value_w, key_w, ws_vwT, ws_kwT);

    gather_kernel<<<MTOK, 256, 0, stream>>>(hash_ids, emb_tables, ws_emb);

    gemm_value_mfma<<<dim3(MTOK / 128, HID / 128), 256, 0, stream>>>(
        ws_emb, ws_vwT, value_b, ws_vraw, ws_pv2);

    gemm_keys_mfma<<<dim3(MTOK / 128, HC * HID / 128), 256, 0, stream>>>(
        ws_emb, ws_kwT, key_b, hidden, norm1_w, norm2_w, ws_psq, ws_pdot);

    mq_kernel<<<MTOK / 4, 256, 0, stream>>>(hidden, ws_mq);

    finalize_kernel<<<(MTOK * HC + 255) / 256, 256, 0, stream>>>(
        ws_psq, ws_pdot, ws_mq, ws_pv2, ws_gate, ws_cc);

    final_kernel<<<MTOK, 256, 0, stream>>>(
        ws_vraw, ws_gate, ws_cc, sc_norm_w, conv_w, out);
}